// Round 1
// 10723.623 us; speedup vs baseline: 2.4630x; 2.4630x over previous
//
#include <hip/hip_runtime.h>
#include <hip/hip_fp16.h>

// ---------------------------------------------------------------------------
// RNN chaotic scan, MI355X.
//   T=512, B=64, I=256, H=2048, O=64, alpha=0.1
// Round theory: scan was latency-bound on agent-scope FENCES (buffer_inv /
// buffer_wbl2 full-L2 maintenance, ~1300/step). This version removes ALL
// fences: every cross-WG payload (partial dumps, r hi/lo staging) moves via
// relaxed agent-scope 8B atomics (sc0/sc1 bypass -> L3 coherence point).
// Ordering: __syncthreads() drains vmcnt before the tid0 flag store
// (release); consumers poll the flag then load in-order (acquire), and sc1
// loads cannot see stale L2 lines since they bypass L2. Arithmetic is
// bit-identical to the previous version (numerics frozen at tolerance edge).
// ---------------------------------------------------------------------------

typedef _Float16 f16;
typedef _Float16 f16x8 __attribute__((ext_vector_type(8)));
typedef float    f32x4 __attribute__((ext_vector_type(4)));
typedef unsigned long long u64;

#define MFMA16(a, b, c) __builtin_amdgcn_mfma_f32_16x16x32_f16((a), (b), (c), 0, 0, 0)

#define OUT0_ELEMS  2097152   // T*B*O floats; rate_all follows in d_out
#define SPIN_BUDGET (1L << 22)

// ws layout (bytes)
#define WS_FLAGP 0            // 256 ints
#define WS_FLAGR 1024         // 32 ints
#define WS_RSTG  4096         // 4 planes x 131072 f16 (buf0 hi, buf0 lo, buf1 hi, buf1 lo)
#define WS_DUMP  (4096 + 1048576)            // 2*32*8*4096 f32 = 8 MB
#define WS_WI    (WS_DUMP + 8388608)         // hi 524288 f16, lo 524288 f16
#define WS_WO    (WS_WI + 2097152)           // 131072 f16

union H8U { f16x8 h; u64 u[2]; };
union F4U { f32x4 f; u64 u[2]; };

__device__ __forceinline__ void cvt_hilo8(const float4 p0, const float4 p1, f16x8& hi, f16x8& lo) {
    float v[8] = {p0.x, p0.y, p0.z, p0.w, p1.x, p1.y, p1.z, p1.w};
#pragma unroll
    for (int j = 0; j < 8; ++j) {
        f16 h = (f16)v[j];
        hi[j] = h;
        lo[j] = (f16)(v[j] - (float)h);
    }
}

__device__ __forceinline__ int ld_flag(int* p) {
    return __hip_atomic_load(p, __ATOMIC_RELAXED, __HIP_MEMORY_SCOPE_AGENT);
}
__device__ __forceinline__ void st_flag(int* p, int v) {
    __hip_atomic_store(p, v, __ATOMIC_RELAXED, __HIP_MEMORY_SCOPE_AGENT);
}
// 8-byte cross-XCD payload movement: relaxed agent atomics -> sc0/sc1 bypass,
// visible at the L3 coherence point without any cache-maintenance fence.
__device__ __forceinline__ u64 ld_u64_sc(const void* p) {
    return __hip_atomic_load((const u64*)p, __ATOMIC_RELAXED, __HIP_MEMORY_SCOPE_AGENT);
}
__device__ __forceinline__ void st_u64_sc(void* p, u64 v) {
    __hip_atomic_store((u64*)p, v, __ATOMIC_RELAXED, __HIP_MEMORY_SCOPE_AGENT);
}
__device__ __forceinline__ void spin_ge(int* p, int target, long& budget) {
    while (budget > 0 && ld_flag(p) < target) {
        --budget;
        __builtin_amdgcn_s_sleep(2);
    }
}

// ------------------------------ prep kernels -------------------------------

__global__ void prep_wi(const float* __restrict__ Wi, f16* __restrict__ hi, f16* __restrict__ lo) {
    const int r    = blockIdx.x * 256 + threadIdx.x;    // [0, 65536)
    const int hblk = r >> 13, rem = r & 8191;
    const int kt = rem >> 10, rem2 = rem & 1023;
    const int nt = rem2 >> 6, lane = rem2 & 63;
    const int h = hblk * 256 + nt * 16 + (lane & 15);
    const int i = kt * 32 + (lane >> 4) * 8;
    const float* p = Wi + (long)h * 256 + i;
    float4 p0 = *(const float4*)p, p1 = *(const float4*)(p + 4);
    f16x8 vh, vl;
    cvt_hilo8(p0, p1, vh, vl);
    *(f16x8*)(hi + (long)r * 8) = vh;
    *(f16x8*)(lo + (long)r * 8) = vl;
}

__global__ void prep_wo(const float* __restrict__ Wo, f16* __restrict__ st) {
    const int r  = blockIdx.x * 256 + threadIdx.x;      // [0, 16384)
    const int nt = r >> 12, rem = r & 4095;
    const int kt = rem >> 6, lane = rem & 63;
    const int o = nt * 16 + (lane & 15);
    const int h = kt * 32 + (lane >> 4) * 8;
    const float* p = Wo + (long)o * 2048 + h;
    float4 p0 = *(const float4*)p, p1 = *(const float4*)(p + 4);
    float v[8] = {p0.x, p0.y, p0.z, p0.w, p1.x, p1.y, p1.z, p1.w};
    f16x8 a;
#pragma unroll
    for (int j = 0; j < 8; ++j) a[j] = (f16)v[j];
    *(f16x8*)(st + (long)r * 8) = a;
}

__global__ void prep_r0(const float* __restrict__ rate0, f16* __restrict__ hi, f16* __restrict__ lo) {
    const int r   = blockIdx.x * 256 + threadIdx.x;     // [0, 16384)
    const int ktg = r >> 8, rem = r & 255;
    const int mt = rem >> 6, lane = rem & 63;
    const int b = mt * 16 + (lane & 15);
    const int k = ktg * 32 + (lane >> 4) * 8;
    const float* p = rate0 + (long)b * 2048 + k;
    float4 p0 = *(const float4*)p, p1 = *(const float4*)(p + 4);
    f16x8 vh, vl;
    cvt_hilo8(p0, p1, vh, vl);
    *(f16x8*)(hi + (long)r * 8) = vh;
    *(f16x8*)(lo + (long)r * 8) = vl;
}

// ------------------------------- pre GEMM ----------------------------------
// pre[row][h] = X[row][:] . Wi[h][:] + bi[h]    row in [0, 32768), h in [0, 2048)

__global__ __launch_bounds__(256, 1) void pre_gemm(const float* __restrict__ X,
                                                   const f16* __restrict__ wih,
                                                   const f16* __restrict__ wil,
                                                   const float* __restrict__ bi,
                                                   float* __restrict__ pre) {
    const int wg = blockIdx.x;                 // 4096
    const int rowblk = wg >> 3, hblk = wg & 7; // hblk == XCD (L2 locality of Wi slice)
    const int tid = threadIdx.x, wv = tid >> 6, l = tid & 63;
    const int l15 = l & 15, lq = l >> 4;

    f16x8 Bh[8][4], Bl[8][4];  // 256 VGPR, persistent
#pragma unroll
    for (int kt = 0; kt < 8; ++kt)
#pragma unroll
        for (int nl = 0; nl < 4; ++nl) {
            const int  nt  = wv * 4 + nl;
            const long idx = (((long)(hblk * 8 + kt) * 16 + nt) * 64 + l) * 8;
            Bh[kt][nl] = *(const f16x8*)(wih + idx);
            Bl[kt][nl] = *(const f16x8*)(wil + idx);
        }
    float biv[4];
#pragma unroll
    for (int nl = 0; nl < 4; ++nl) biv[nl] = bi[hblk * 256 + (wv * 4 + nl) * 16 + l15];

#pragma unroll
    for (int mt = 0; mt < 4; ++mt) {
        const float* ap = X + (long)(rowblk * 64 + mt * 16 + l15) * 256 + lq * 8;
        f16x8 Ah[8], Al[8];
#pragma unroll
        for (int kt = 0; kt < 8; ++kt) {
            float4 p0 = *(const float4*)(ap + kt * 32);
            float4 p1 = *(const float4*)(ap + kt * 32 + 4);
            cvt_hilo8(p0, p1, Ah[kt], Al[kt]);
        }
        f32x4 acc[4] = {{0, 0, 0, 0}, {0, 0, 0, 0}, {0, 0, 0, 0}, {0, 0, 0, 0}};
#pragma unroll
        for (int kt = 0; kt < 8; ++kt)
#pragma unroll
            for (int nl = 0; nl < 4; ++nl) {
                acc[nl] = MFMA16(Al[kt], Bh[kt][nl], acc[nl]);
                acc[nl] = MFMA16(Ah[kt], Bl[kt][nl], acc[nl]);
                acc[nl] = MFMA16(Ah[kt], Bh[kt][nl], acc[nl]);
            }
#pragma unroll
        for (int nl = 0; nl < 4; ++nl)
#pragma unroll
            for (int q = 0; q < 4; ++q) {
                const int row = rowblk * 64 + mt * 16 + lq * 4 + q;
                const int h   = hblk * 256 + (wv * 4 + nl) * 16 + l15;
                pre[(long)row * 2048 + h] = acc[nl][q] + biv[nl];
            }
    }
}

// ------------------------------ scan kernel --------------------------------
// 256 WGs: hp = wg>>3 (h-slice of 64), s = wg&7 (k-shard of 256; == XCD).
// flagR[g] = t  <=> r_state(t) slice g published.  flagP[hp][s] = t+1 <=> partial(t) dumped.
// No fences anywhere: payloads are sc1 (agent-relaxed) atomics; release via
// __syncthreads (vmcnt drain) + flag store; acquire via in-order poll->load.

__global__ __launch_bounds__(256, 1) void scan_kernel(const float* __restrict__ Wh,
                                                      const float* __restrict__ bhp,
                                                      const float* __restrict__ rate0,
                                                      float* __restrict__ ra,   // pre in, rate_all out (in-place)
                                                      f16* __restrict__ rh0, f16* __restrict__ rl0,
                                                      f16* __restrict__ rh1, f16* __restrict__ rl1,
                                                      float* __restrict__ dumps,
                                                      int* flagP, int* flagR) {
    const int wg = blockIdx.x;
    const int hp = wg >> 3, s = wg & 7;
    const int tid = threadIdx.x, wv = tid >> 6, l = tid & 63;
    const int l15 = l & 15, lq = l >> 4;
    const bool is_red = (s == (hp & 7));
    __shared__ float lds[64 * 68];

    // Wh tile -> registers (hi/lo f16 frags). 256 VGPR, lives across all steps.
    f16x8 WhH[8][4], WhL[8][4];
#pragma unroll
    for (int kt = 0; kt < 8; ++kt)
#pragma unroll
        for (int nt = 0; nt < 4; ++nt) {
            const float* p = Wh + (long)(hp * 64 + nt * 16 + l15) * 2048 + s * 256 + kt * 32 + lq * 8;
            float4 p0 = *(const float4*)p, p1 = *(const float4*)(p + 4);
            cvt_hilo8(p0, p1, WhH[kt][nt], WhL[kt][nt]);
        }

    float rf[4][4];  // f32 master state (reducers only), D-frag layout
    float bhv[4];
    if (is_red) {
#pragma unroll
        for (int nt = 0; nt < 4; ++nt) {
            bhv[nt] = bhp[hp * 64 + nt * 16 + l15];
#pragma unroll
            for (int q = 0; q < 4; ++q)
                rf[nt][q] = rate0[(long)(wv * 16 + lq * 4 + q) * 2048 + hp * 64 + nt * 16 + l15];
        }
    }

    long budget = SPIN_BUDGET;

    for (int t = 0; t < 512; ++t) {
        // prefetch pre[t] slice (reducers) - normal cached loads, written by a
        // prior kernel; independent of flags, hides HBM latency
        float pr[4][4];
        if (is_red) {
#pragma unroll
            for (int nt = 0; nt < 4; ++nt)
#pragma unroll
                for (int q = 0; q < 4; ++q)
                    pr[nt][q] = ra[((long)t * 64 + wv * 16 + lq * 4 + q) * 2048 + hp * 64 + nt * 16 + l15];
        }

        const f16* rh = (t & 1) ? rh1 : rh0;
        const f16* rl = (t & 1) ? rl1 : rl0;
        f32x4 acc[4] = {{0, 0, 0, 0}, {0, 0, 0, 0}, {0, 0, 0, 0}, {0, 0, 0, 0}};

#pragma unroll
        for (int i = 0; i < 4; ++i) {  // consume r slices incrementally as they arrive
            spin_ge(flagR + 4 * s + i, t, budget);
            // no fence: staging loads below bypass L2 (sc1) and issue in
            // wave-order after the poll resolved -> acquire semantics hold
#pragma unroll
            for (int kk = 0; kk < 2; ++kk) {
                const int  ktl  = 2 * i + kk;
                const long boff = (((long)((s * 8 + ktl) * 4 + wv) * 64 + l) * 8) * 2;  // bytes
                H8U ah, al;
                ah.u[0] = ld_u64_sc((const char*)rh + boff);
                ah.u[1] = ld_u64_sc((const char*)rh + boff + 8);
                al.u[0] = ld_u64_sc((const char*)rl + boff);
                al.u[1] = ld_u64_sc((const char*)rl + boff + 8);
#pragma unroll
                for (int nt = 0; nt < 4; ++nt) {
                    acc[nt] = MFMA16(al.h, WhH[ktl][nt], acc[nt]);
                    acc[nt] = MFMA16(ah.h, WhL[ktl][nt], acc[nt]);
                    acc[nt] = MFMA16(ah.h, WhH[ktl][nt], acc[nt]);
                }
            }
        }

        // dump raw accumulator via sc1 stores (straight to L3 coherence point)
        {
            char* dp = (char*)(dumps + ((long)(t & 1) * 256 + hp * 8 + s) * 4096 + tid * 16);
#pragma unroll
            for (int nt = 0; nt < 4; ++nt) {
                F4U v; v.f = acc[nt];
                st_u64_sc(dp + nt * 16,     v.u[0]);
                st_u64_sc(dp + nt * 16 + 8, v.u[1]);
            }
        }
        __syncthreads();  // compiler drains vmcnt(0) before s_barrier -> stores visible
        if (tid == 0) st_flag(flagP + hp * 8 + s, t + 1);

        if (is_red) {
            // lane-parallel wait: lanes poll the 8 shard flags (tid&7);
            // each wave proceeds once all 8 observed by its own lanes.
            {
                int* fp = flagP + hp * 8 + (tid & 7);
                while (budget > 0 && !__all(ld_flag(fp) >= t + 1)) {
                    --budget;
                    __builtin_amdgcn_s_sleep(2);
                }
            }

            float u[4][4] = {};
            const char* db = (const char*)(dumps + ((long)(t & 1) * 256 + hp * 8) * 4096 + tid * 16);
#pragma unroll
            for (int nt = 0; nt < 4; ++nt) {
                F4U v[8];
#pragma unroll
                for (int ss = 0; ss < 8; ++ss) {
                    v[ss].u[0] = ld_u64_sc(db + (long)ss * 16384 + nt * 16);
                    v[ss].u[1] = ld_u64_sc(db + (long)ss * 16384 + nt * 16 + 8);
                }
#pragma unroll
                for (int ss = 0; ss < 8; ++ss) {  // same add order as before (ss ascending)
                    u[nt][0] += v[ss].f[0]; u[nt][1] += v[ss].f[1];
                    u[nt][2] += v[ss].f[2]; u[nt][3] += v[ss].f[3];
                }
            }
#pragma unroll
            for (int nt = 0; nt < 4; ++nt)
#pragma unroll
                for (int q = 0; q < 4; ++q) {
                    const float uu = u[nt][q] + pr[nt][q] + bhv[nt];
                    const float rn = tanhf(uu);
                    rf[nt][q] = 0.9f * rf[nt][q] + 0.1f * rn;
                }

            // transpose D-frag -> A-frag layout via LDS, republish hi/lo f16
            // (publish FIRST; rate_all HBM write moved off the critical path)
#pragma unroll
            for (int nt = 0; nt < 4; ++nt)
#pragma unroll
                for (int q = 0; q < 4; ++q)
                    lds[(wv * 16 + lq * 4 + q) * 68 + nt * 16 + l15] = rf[nt][q];
            __syncthreads();
            f16* wh_ = (t & 1) ? rh0 : rh1;  // buffer (t+1)&1
            f16* wl_ = (t & 1) ? rl0 : rl1;
#pragma unroll
            for (int i2 = 0; i2 < 2; ++i2) {
                const int c = tid + i2 * 256;
                const int b = c & 63, h8 = c >> 6;
                const float* lp = lds + b * 68 + h8 * 8;
                float4 p0 = *(const float4*)lp, p1 = *(const float4*)(lp + 4);
                H8U hi8, lo8;
                cvt_hilo8(p0, p1, hi8.h, lo8.h);
                const int  k0   = hp * 64 + h8 * 8;
                const long bo2  = (((long)((k0 >> 5) * 4 + (b >> 4)) * 64 + ((b & 15) | (((k0 >> 3) & 3) << 4))) * 8) * 2;
                st_u64_sc((char*)wh_ + bo2,     hi8.u[0]);
                st_u64_sc((char*)wh_ + bo2 + 8, hi8.u[1]);
                st_u64_sc((char*)wl_ + bo2,     lo8.u[0]);
                st_u64_sc((char*)wl_ + bo2 + 8, lo8.u[1]);
            }
            __syncthreads();  // vmcnt drained -> staging visible before flag
            if (tid == 0) st_flag(flagR + hp, t + 1);

            // rate_all write (normal cached stores; only read by out_gemm after
            // kernel end) - off the critical path now
#pragma unroll
            for (int nt = 0; nt < 4; ++nt)
#pragma unroll
                for (int q = 0; q < 4; ++q)
                    ra[((long)t * 64 + wv * 16 + lq * 4 + q) * 2048 + hp * 64 + nt * 16 + l15] = rf[nt][q];
        }
    }
}

// ------------------------------- out GEMM ----------------------------------
// out[row][o] = rate_all[row][:] . Wo[o][:] + bo[o]

__global__ __launch_bounds__(256, 1) void out_gemm(const float* __restrict__ ra,
                                                   const f16* __restrict__ wo,
                                                   const float* __restrict__ bo,
                                                   float* __restrict__ out) {
    const int wg = blockIdx.x, tid = threadIdx.x, wv = tid >> 6, l = tid & 63;
    const int l15 = l & 15, lq = l >> 4;
    const long rowbase = (long)wg * 64;
    f32x4 acc[4] = {{0, 0, 0, 0}, {0, 0, 0, 0}, {0, 0, 0, 0}, {0, 0, 0, 0}};
    const float bov = bo[wv * 16 + l15];
#pragma unroll 4
    for (int kt = 0; kt < 64; ++kt) {
        f16x8 B = *(const f16x8*)(wo + ((long)(wv * 64 + kt) * 64 + l) * 8);
#pragma unroll
        for (int mt = 0; mt < 4; ++mt) {
            const float* ap = ra + (rowbase + mt * 16 + l15) * 2048 + kt * 32 + lq * 8;
            float4 p0 = *(const float4*)ap, p1 = *(const float4*)(ap + 4);
            float v[8] = {p0.x, p0.y, p0.z, p0.w, p1.x, p1.y, p1.z, p1.w};
            f16x8 a;
#pragma unroll
            for (int j = 0; j < 8; ++j) a[j] = (f16)v[j];
            acc[mt] = MFMA16(a, B, acc[mt]);
        }
    }
#pragma unroll
    for (int mt = 0; mt < 4; ++mt)
#pragma unroll
        for (int q = 0; q < 4; ++q)
            out[(rowbase + mt * 16 + lq * 4 + q) * 64 + wv * 16 + l15] = acc[mt][q] + bov;
}

// ------------------------------ launch -------------------------------------

extern "C" void kernel_launch(void* const* d_in, const int* in_sizes, int n_in,
                              void* d_out, int out_size, void* d_ws, size_t ws_size,
                              hipStream_t stream) {
    const float* input = (const float*)d_in[0];
    const float* rate0 = (const float*)d_in[1];
    const float* Wi    = (const float*)d_in[2];
    const float* bi    = (const float*)d_in[3];
    const float* Wh    = (const float*)d_in[4];
    const float* bh    = (const float*)d_in[5];
    const float* Wo    = (const float*)d_in[6];
    const float* bo    = (const float*)d_in[7];

    float* out      = (float*)d_out;
    float* rate_all = out + OUT0_ELEMS;  // pre written here, then overwritten in place

    char* w      = (char*)d_ws;
    int*  flagP  = (int*)(w + WS_FLAGP);
    int*  flagR  = (int*)(w + WS_FLAGR);
    f16*  rs     = (f16*)(w + WS_RSTG);
    f16*  rh0    = rs;
    f16*  rl0    = rs + 131072;
    f16*  rh1    = rs + 262144;
    f16*  rl1    = rs + 393216;
    float* dumps = (float*)(w + WS_DUMP);
    f16*  wi_hi  = (f16*)(w + WS_WI);
    f16*  wi_lo  = wi_hi + 524288;
    f16*  wo_st  = (f16*)(w + WS_WO);

    hipMemsetAsync(d_ws, 0, 4096, stream);  // zero flags every launch
    prep_wi<<<256, 256, 0, stream>>>(Wi, wi_hi, wi_lo);
    prep_wo<<<64, 256, 0, stream>>>(Wo, wo_st);
    prep_r0<<<64, 256, 0, stream>>>(rate0, rh0, rl0);
    pre_gemm<<<4096, 256, 0, stream>>>(input, wi_hi, wi_lo, bi, rate_all);
    scan_kernel<<<256, 256, 0, stream>>>(Wh, bh, rate0, rate_all,
                                         rh0, rl0, rh1, rl1, dumps, flagP, flagR);
    out_gemm<<<512, 256, 0, stream>>>(rate_all, wo_st, bo, out);
}

// Round 3
// 9974.490 us; speedup vs baseline: 2.6480x; 1.0751x over previous
//
#include <hip/hip_runtime.h>
#include <hip/hip_fp16.h>

// ---------------------------------------------------------------------------
// RNN chaotic scan, MI355X.
//   T=512, B=64, I=256, H=2048, O=64, alpha=0.1
// R3: R2 proved plain sc0/sc1 stores ack vmcnt BEFORE reaching the coherence
// point (raced, absmax 2.57). Payloads are back to the R1-proven class:
// 8B relaxed agent-scope atomics (ack at LLC => __syncthreads-drain + flag
// store is a sound release). R1's 3.6x write amplification is fixed by
// LAYOUT instead: dump tiles and r-staging are stored as u64 PLANES so each
// store instruction's 64 lanes cover a contiguous 512B (dumps) / 128B
// (staging) run -> adjacent-granule writes merge into full sectors.
// Reducer keeps its own shard in registers (skips own dump+flag+readback;
// FP sum order preserved by in-place substitution). Bit-identical numerics.
// ---------------------------------------------------------------------------

typedef _Float16 f16;
typedef _Float16 f16x8 __attribute__((ext_vector_type(8)));
typedef float    f32x4 __attribute__((ext_vector_type(4)));
typedef unsigned long long u64;

#define MFMA16(a, b, c) __builtin_amdgcn_mfma_f32_16x16x32_f16((a), (b), (c), 0, 0, 0)

#define OUT0_ELEMS  2097152   // T*B*O floats; rate_all follows in d_out
#define SPIN_BUDGET (1L << 22)

// ws layout (bytes)
#define WS_FLAGP 0            // 256 ints
#define WS_FLAGR 1024         // 32 ints
#define WS_RSTG  4096         // 2 parities x 4 planes x 16384 u64 = 1 MB
#define WS_DUMP  (4096 + 1048576)            // 2*32*8*2048 u64 = 8 MB
#define WS_WI    (WS_DUMP + 8388608)         // hi 524288 f16, lo 524288 f16
#define WS_WO    (WS_WI + 2097152)           // 131072 f16

// staging plane offsets (u64 units) within one parity block of 65536
#define SP_HIA 0
#define SP_HIB 16384
#define SP_LOA 32768
#define SP_LOB 49152

union H8U { f16x8 h; u64 u[2]; };
union F4U { f32x4 f; u64 u[2]; };

__device__ __forceinline__ void cvt_hilo8(const float4 p0, const float4 p1, f16x8& hi, f16x8& lo) {
    float v[8] = {p0.x, p0.y, p0.z, p0.w, p1.x, p1.y, p1.z, p1.w};
#pragma unroll
    for (int j = 0; j < 8; ++j) {
        f16 h = (f16)v[j];
        hi[j] = h;
        lo[j] = (f16)(v[j] - (float)h);
    }
}

__device__ __forceinline__ int ld_flag(int* p) {
    return __hip_atomic_load(p, __ATOMIC_RELAXED, __HIP_MEMORY_SCOPE_AGENT);
}
__device__ __forceinline__ void st_flag(int* p, int v) {
    __hip_atomic_store(p, v, __ATOMIC_RELAXED, __HIP_MEMORY_SCOPE_AGENT);
}
// 8B cross-XCD payload movement: relaxed agent atomics (R1-proven class;
// ack at the coherence point -> vmcnt drain implies global visibility).
__device__ __forceinline__ u64 ld_u64a(const u64* p) {
    return __hip_atomic_load(p, __ATOMIC_RELAXED, __HIP_MEMORY_SCOPE_AGENT);
}
__device__ __forceinline__ void st_u64a(u64* p, u64 v) {
    __hip_atomic_store(p, v, __ATOMIC_RELAXED, __HIP_MEMORY_SCOPE_AGENT);
}
__device__ __forceinline__ void spin_ge(int* p, int target, long& budget) {
    while (budget > 0 && ld_flag(p) < target) {
        --budget;
        __builtin_amdgcn_s_sleep(2);
    }
}

// ------------------------------ prep kernels -------------------------------

__global__ void prep_wi(const float* __restrict__ Wi, f16* __restrict__ hi, f16* __restrict__ lo) {
    const int r    = blockIdx.x * 256 + threadIdx.x;    // [0, 65536)
    const int hblk = r >> 13, rem = r & 8191;
    const int kt = rem >> 10, rem2 = rem & 1023;
    const int nt = rem2 >> 6, lane = rem2 & 63;
    const int h = hblk * 256 + nt * 16 + (lane & 15);
    const int i = kt * 32 + (lane >> 4) * 8;
    const float* p = Wi + (long)h * 256 + i;
    float4 p0 = *(const float4*)p, p1 = *(const float4*)(p + 4);
    f16x8 vh, vl;
    cvt_hilo8(p0, p1, vh, vl);
    *(f16x8*)(hi + (long)r * 8) = vh;
    *(f16x8*)(lo + (long)r * 8) = vl;
}

__global__ void prep_wo(const float* __restrict__ Wo, f16* __restrict__ st) {
    const int r  = blockIdx.x * 256 + threadIdx.x;      // [0, 16384)
    const int nt = r >> 12, rem = r & 4095;
    const int kt = rem >> 6, lane = rem & 63;
    const int o = nt * 16 + (lane & 15);
    const int h = kt * 32 + (lane >> 4) * 8;
    const float* p = Wo + (long)o * 2048 + h;
    float4 p0 = *(const float4*)p, p1 = *(const float4*)(p + 4);
    float v[8] = {p0.x, p0.y, p0.z, p0.w, p1.x, p1.y, p1.z, p1.w};
    f16x8 a;
#pragma unroll
    for (int j = 0; j < 8; ++j) a[j] = (f16)v[j];
    *(f16x8*)(st + (long)r * 8) = a;
}

// writes the initial r-state staging in the NEW plane layout (parity 0)
__global__ void prep_r0(const float* __restrict__ rate0, u64* __restrict__ rsU) {
    const int r   = blockIdx.x * 256 + threadIdx.x;     // frag index [0, 16384)
    const int ktg = r >> 8, rem = r & 255;
    const int mt = rem >> 6, lane = rem & 63;
    const int b = mt * 16 + (lane & 15);
    const int k = ktg * 32 + (lane >> 4) * 8;
    const float* p = rate0 + (long)b * 2048 + k;
    float4 p0 = *(const float4*)p, p1 = *(const float4*)(p + 4);
    H8U vh, vl;
    cvt_hilo8(p0, p1, vh.h, vl.h);
    rsU[SP_HIA + r] = vh.u[0];
    rsU[SP_HIB + r] = vh.u[1];
    rsU[SP_LOA + r] = vl.u[0];
    rsU[SP_LOB + r] = vl.u[1];
}

// ------------------------------- pre GEMM ----------------------------------
// pre[row][h] = X[row][:] . Wi[h][:] + bi[h]    row in [0, 32768), h in [0, 2048)

__global__ __launch_bounds__(256, 1) void pre_gemm(const float* __restrict__ X,
                                                   const f16* __restrict__ wih,
                                                   const f16* __restrict__ wil,
                                                   const float* __restrict__ bi,
                                                   float* __restrict__ pre) {
    const int wg = blockIdx.x;                 // 4096
    const int rowblk = wg >> 3, hblk = wg & 7; // hblk == XCD (L2 locality of Wi slice)
    const int tid = threadIdx.x, wv = tid >> 6, l = tid & 63;
    const int l15 = l & 15, lq = l >> 4;

    f16x8 Bh[8][4], Bl[8][4];  // 256 VGPR, persistent
#pragma unroll
    for (int kt = 0; kt < 8; ++kt)
#pragma unroll
        for (int nl = 0; nl < 4; ++nl) {
            const int  nt  = wv * 4 + nl;
            const long idx = (((long)(hblk * 8 + kt) * 16 + nt) * 64 + l) * 8;
            Bh[kt][nl] = *(const f16x8*)(wih + idx);
            Bl[kt][nl] = *(const f16x8*)(wil + idx);
        }
    float biv[4];
#pragma unroll
    for (int nl = 0; nl < 4; ++nl) biv[nl] = bi[hblk * 256 + (wv * 4 + nl) * 16 + l15];

#pragma unroll
    for (int mt = 0; mt < 4; ++mt) {
        const float* ap = X + (long)(rowblk * 64 + mt * 16 + l15) * 256 + lq * 8;
        f16x8 Ah[8], Al[8];
#pragma unroll
        for (int kt = 0; kt < 8; ++kt) {
            float4 p0 = *(const float4*)(ap + kt * 32);
            float4 p1 = *(const float4*)(ap + kt * 32 + 4);
            cvt_hilo8(p0, p1, Ah[kt], Al[kt]);
        }
        f32x4 acc[4] = {{0, 0, 0, 0}, {0, 0, 0, 0}, {0, 0, 0, 0}, {0, 0, 0, 0}};
#pragma unroll
        for (int kt = 0; kt < 8; ++kt)
#pragma unroll
            for (int nl = 0; nl < 4; ++nl) {
                acc[nl] = MFMA16(Al[kt], Bh[kt][nl], acc[nl]);
                acc[nl] = MFMA16(Ah[kt], Bl[kt][nl], acc[nl]);
                acc[nl] = MFMA16(Ah[kt], Bh[kt][nl], acc[nl]);
            }
#pragma unroll
        for (int nl = 0; nl < 4; ++nl)
#pragma unroll
            for (int q = 0; q < 4; ++q) {
                const int row = rowblk * 64 + mt * 16 + lq * 4 + q;
                const int h   = hblk * 256 + (wv * 4 + nl) * 16 + l15;
                pre[(long)row * 2048 + h] = acc[nl][q] + biv[nl];
            }
    }
}

// ------------------------------ scan kernel --------------------------------
// 256 WGs: hp = wg>>3 (h-slice of 64), s = wg&7 (k-shard of 256; == XCD).
// flagR[g] = t  <=> r_state(t) slice g published.  flagP[hp][s] = t+1 <=> partial(t) dumped.
// Payloads: 8B relaxed agent atomics laid out in u64 PLANES so each store
// instruction's lanes are address-contiguous (full-sector merge downstream).
// Release: payload atomics -> __syncthreads (vmcnt drain) -> flag store.
// Acquire: flag poll -> sched_barrier -> payload atomic loads (in order).

__global__ __launch_bounds__(256, 1) void scan_kernel(const float* __restrict__ Wh,
                                                      const float* __restrict__ bhp,
                                                      const float* __restrict__ rate0,
                                                      float* __restrict__ ra,   // pre in, rate_all out (in-place)
                                                      u64* __restrict__ rsU,    // staging planes, 2 parities
                                                      u64* __restrict__ dumpU,  // dump planes, 2 parities
                                                      int* flagP, int* flagR) {
    const int wg = blockIdx.x;
    const int hp = wg >> 3, s = wg & 7;
    const int tid = threadIdx.x, wv = tid >> 6, l = tid & 63;
    const int l15 = l & 15, lq = l >> 4;
    const bool is_red = (s == (hp & 7));
    __shared__ float lds[64 * 68];

    // Wh tile -> registers (hi/lo f16 frags). Lives across all steps.
    f16x8 WhH[8][4], WhL[8][4];
#pragma unroll
    for (int kt = 0; kt < 8; ++kt)
#pragma unroll
        for (int nt = 0; nt < 4; ++nt) {
            const float* p = Wh + (long)(hp * 64 + nt * 16 + l15) * 2048 + s * 256 + kt * 32 + lq * 8;
            float4 p0 = *(const float4*)p, p1 = *(const float4*)(p + 4);
            cvt_hilo8(p0, p1, WhH[kt][nt], WhL[kt][nt]);
        }

    float rf[4][4];  // f32 master state (reducers only), D-frag layout
    float bhv[4];
    if (is_red) {
#pragma unroll
        for (int nt = 0; nt < 4; ++nt) {
            bhv[nt] = bhp[hp * 64 + nt * 16 + l15];
#pragma unroll
            for (int q = 0; q < 4; ++q)
                rf[nt][q] = rate0[(long)(wv * 16 + lq * 4 + q) * 2048 + hp * 64 + nt * 16 + l15];
        }
    }

    long budget = SPIN_BUDGET;

    for (int t = 0; t < 512; ++t) {
        // prefetch pre[t] slice (reducers) - normal cached loads, written by a
        // prior kernel; overlaps the spins below.
        float pr[4][4];
        if (is_red) {
#pragma unroll
            for (int nt = 0; nt < 4; ++nt)
#pragma unroll
                for (int q = 0; q < 4; ++q)
                    pr[nt][q] = ra[((long)t * 64 + wv * 16 + lq * 4 + q) * 2048 + hp * 64 + nt * 16 + l15];
        }

        const u64* sb = rsU + (long)(t & 1) * 65536;   // staging parity block
        f32x4 acc[4] = {{0, 0, 0, 0}, {0, 0, 0, 0}, {0, 0, 0, 0}, {0, 0, 0, 0}};

#pragma unroll
        for (int i = 0; i < 4; ++i) {  // consume r slices incrementally as they arrive
            spin_ge(flagR + 4 * s + i, t, budget);
            __builtin_amdgcn_sched_barrier(0);
#pragma unroll
            for (int kk = 0; kk < 2; ++kk) {
                const int ktl = 2 * i + kk;
                const int f   = ((s * 8 + ktl) * 4 + wv) * 64 + l;   // frag index
                H8U ah, al;
                ah.u[0] = ld_u64a(sb + SP_HIA + f);
                ah.u[1] = ld_u64a(sb + SP_HIB + f);
                al.u[0] = ld_u64a(sb + SP_LOA + f);
                al.u[1] = ld_u64a(sb + SP_LOB + f);
#pragma unroll
                for (int nt = 0; nt < 4; ++nt) {
                    acc[nt] = MFMA16(al.h, WhH[ktl][nt], acc[nt]);
                    acc[nt] = MFMA16(ah.h, WhL[ktl][nt], acc[nt]);
                    acc[nt] = MFMA16(ah.h, WhH[ktl][nt], acc[nt]);
                }
            }
        }

        if (!is_red) {
            // dump accumulator in plane layout [j][tid]: per-instruction 64
            // lanes x 8B contiguous -> full-sector write bursts
            u64* dp = dumpU + ((long)(t & 1) * 256 + hp * 8 + s) * 2048;
#pragma unroll
            for (int nt = 0; nt < 4; ++nt) {
                F4U v; v.f = acc[nt];
                st_u64a(dp + (2 * nt + 0) * 256 + tid, v.u[0]);
                st_u64a(dp + (2 * nt + 1) * 256 + tid, v.u[1]);
            }
            __syncthreads();  // drains vmcnt -> atomics complete at LLC
            if (tid == 0) st_flag(flagP + hp * 8 + s, t + 1);
        } else {
            // lane-parallel wait for the 7 other shards (own shard in regs)
            {
                const int ss7  = tid & 7;
                const bool own = (ss7 == s);
                int* fp = flagP + hp * 8 + ss7;
                while (budget > 0 && !__all(own || (ld_flag(fp) >= t + 1))) {
                    --budget;
                    __builtin_amdgcn_s_sleep(2);
                }
                __builtin_amdgcn_sched_barrier(0);
            }

            float u[4][4];
            const u64* db = dumpU + ((long)(t & 1) * 256 + hp * 8) * 2048;
#pragma unroll
            for (int nt = 0; nt < 4; ++nt) {
                F4U w[8];
#pragma unroll
                for (int ss = 0; ss < 8; ++ss)
                    if (ss != s) {
                        w[ss].u[0] = ld_u64a(db + (long)ss * 2048 + (2 * nt + 0) * 256 + tid);
                        w[ss].u[1] = ld_u64a(db + (long)ss * 2048 + (2 * nt + 1) * 256 + tid);
                    }
                float s0 = 0.f, s1 = 0.f, s2 = 0.f, s3 = 0.f;
#pragma unroll
                for (int ss = 0; ss < 8; ++ss) {  // ss ascending: FP order identical to R1
                    f32x4 x = (ss == s) ? acc[nt] : w[ss].f;
                    s0 += x[0]; s1 += x[1]; s2 += x[2]; s3 += x[3];
                }
                u[nt][0] = s0; u[nt][1] = s1; u[nt][2] = s2; u[nt][3] = s3;
            }

#pragma unroll
            for (int nt = 0; nt < 4; ++nt)
#pragma unroll
                for (int q = 0; q < 4; ++q) {
                    const float uu = u[nt][q] + pr[nt][q] + bhv[nt];
                    const float rn = tanhf(uu);
                    rf[nt][q] = 0.9f * rf[nt][q] + 0.1f * rn;
                }

            // transpose D-frag -> A-frag layout via LDS, republish hi/lo f16
            // planes (publish FIRST; rate_all HBM write off the critical path)
#pragma unroll
            for (int nt = 0; nt < 4; ++nt)
#pragma unroll
                for (int q = 0; q < 4; ++q)
                    lds[(wv * 16 + lq * 4 + q) * 68 + nt * 16 + l15] = rf[nt][q];
            __syncthreads();
            u64* sbn = rsU + (long)((t + 1) & 1) * 65536;
#pragma unroll
            for (int i2 = 0; i2 < 2; ++i2) {
                const int c = tid + i2 * 256;
                const int b = c & 63, h8 = c >> 6;
                const float* lp = lds + b * 68 + h8 * 8;
                float4 p0 = *(const float4*)lp, p1 = *(const float4*)(lp + 4);
                H8U hi8, lo8;
                cvt_hilo8(p0, p1, hi8.h, lo8.h);
                const int k0 = hp * 64 + h8 * 8;
                const int f  = ((k0 >> 5) * 4 + (b >> 4)) * 64 + ((b & 15) | (((k0 >> 3) & 3) << 4));
                st_u64a(sbn + SP_HIA + f, hi8.u[0]);
                st_u64a(sbn + SP_HIB + f, hi8.u[1]);
                st_u64a(sbn + SP_LOA + f, lo8.u[0]);
                st_u64a(sbn + SP_LOB + f, lo8.u[1]);
            }
            __syncthreads();  // all staging atomics drained across the WG
            if (tid == 0) st_flag(flagR + hp, t + 1);

            // rate_all write (normal cached stores; only read by out_gemm
            // after kernel end) - off the critical path
#pragma unroll
            for (int nt = 0; nt < 4; ++nt)
#pragma unroll
                for (int q = 0; q < 4; ++q)
                    ra[((long)t * 64 + wv * 16 + lq * 4 + q) * 2048 + hp * 64 + nt * 16 + l15] = rf[nt][q];
        }
    }
}

// ------------------------------- out GEMM ----------------------------------
// out[row][o] = rate_all[row][:] . Wo[o][:] + bo[o]

__global__ __launch_bounds__(256, 1) void out_gemm(const float* __restrict__ ra,
                                                   const f16* __restrict__ wo,
                                                   const float* __restrict__ bo,
                                                   float* __restrict__ out) {
    const int wg = blockIdx.x, tid = threadIdx.x, wv = tid >> 6, l = tid & 63;
    const int l15 = l & 15, lq = l >> 4;
    const long rowbase = (long)wg * 64;
    f32x4 acc[4] = {{0, 0, 0, 0}, {0, 0, 0, 0}, {0, 0, 0, 0}, {0, 0, 0, 0}};
    const float bov = bo[wv * 16 + l15];
#pragma unroll 4
    for (int kt = 0; kt < 64; ++kt) {
        f16x8 B = *(const f16x8*)(wo + ((long)(wv * 64 + kt) * 64 + l) * 8);
#pragma unroll
        for (int mt = 0; mt < 4; ++mt) {
            const float* ap = ra + (rowbase + mt * 16 + l15) * 2048 + kt * 32 + lq * 8;
            float4 p0 = *(const float4*)ap, p1 = *(const float4*)(ap + 4);
            float v[8] = {p0.x, p0.y, p0.z, p0.w, p1.x, p1.y, p1.z, p1.w};
            f16x8 a;
#pragma unroll
            for (int j = 0; j < 8; ++j) a[j] = (f16)v[j];
            acc[mt] = MFMA16(a, B, acc[mt]);
        }
    }
#pragma unroll
    for (int mt = 0; mt < 4; ++mt)
#pragma unroll
        for (int q = 0; q < 4; ++q)
            out[(rowbase + mt * 16 + lq * 4 + q) * 64 + wv * 16 + l15] = acc[mt][q] + bov;
}

// ------------------------------ launch -------------------------------------

extern "C" void kernel_launch(void* const* d_in, const int* in_sizes, int n_in,
                              void* d_out, int out_size, void* d_ws, size_t ws_size,
                              hipStream_t stream) {
    const float* input = (const float*)d_in[0];
    const float* rate0 = (const float*)d_in[1];
    const float* Wi    = (const float*)d_in[2];
    const float* bi    = (const float*)d_in[3];
    const float* Wh    = (const float*)d_in[4];
    const float* bh    = (const float*)d_in[5];
    const float* Wo    = (const float*)d_in[6];
    const float* bo    = (const float*)d_in[7];

    float* out      = (float*)d_out;
    float* rate_all = out + OUT0_ELEMS;  // pre written here, then overwritten in place

    char* w      = (char*)d_ws;
    int*  flagP  = (int*)(w + WS_FLAGP);
    int*  flagR  = (int*)(w + WS_FLAGR);
    u64*  rsU    = (u64*)(w + WS_RSTG);
    u64*  dumpU  = (u64*)(w + WS_DUMP);
    f16*  wi_hi  = (f16*)(w + WS_WI);
    f16*  wi_lo  = wi_hi + 524288;
    f16*  wo_st  = (f16*)(w + WS_WO);

    hipMemsetAsync(d_ws, 0, 4096, stream);  // zero flags every launch
    prep_wi<<<256, 256, 0, stream>>>(Wi, wi_hi, wi_lo);
    prep_wo<<<64, 256, 0, stream>>>(Wo, wo_st);
    prep_r0<<<64, 256, 0, stream>>>(rate0, rsU);
    pre_gemm<<<4096, 256, 0, stream>>>(input, wi_hi, wi_lo, bi, rate_all);
    scan_kernel<<<256, 256, 0, stream>>>(Wh, bh, rate0, rate_all,
                                         rsU, dumpU, flagP, flagR);
    out_gemm<<<512, 256, 0, stream>>>(rate_all, wo_st, bo, out);
}

// Round 4
// 6600.903 us; speedup vs baseline: 4.0014x; 1.5111x over previous
//
#include <hip/hip_runtime.h>
#include <hip/hip_fp16.h>

// ---------------------------------------------------------------------------
// RNN chaotic scan, MI355X.
//   T=512, B=64, I=256, H=2048, O=64, alpha=0.1
// R4: R3 showed time tracks ATOMIC OP COUNT (~3M/step), not bytes (WRITE_SIZE
// fix gave no speedup). Atomics don't coalesce: every lane's 8B op is one LLC
// transaction. Only the STORE side needs atomic class (R2: plain sc stores
// ack vmcnt early -> unsound release; R1/R3: atomic stores + barrier + flag
// is sound). READ side after a flag poll only needs "read at the coherence
// point": plain global_load_dwordx2 sc0 sc1 (bypass L1/L2, read L3) --
// pipelined + wave-coalesced. This round converts ALL cross-WG payload READS
// to plain sc loads (explicit vmcnt(0)+sched_barrier before use, rule #18).
// Stores/flags/layouts/FP-order unchanged from R3 -> bit-identical numerics.
// ---------------------------------------------------------------------------

typedef _Float16 f16;
typedef _Float16 f16x8 __attribute__((ext_vector_type(8)));
typedef float    f32x4 __attribute__((ext_vector_type(4)));
typedef unsigned long long u64;

#define MFMA16(a, b, c) __builtin_amdgcn_mfma_f32_16x16x32_f16((a), (b), (c), 0, 0, 0)

#define OUT0_ELEMS  2097152   // T*B*O floats; rate_all follows in d_out
#define SPIN_BUDGET (1L << 22)

// ws layout (bytes)
#define WS_FLAGP 0            // 256 ints
#define WS_FLAGR 1024         // 32 ints
#define WS_RSTG  4096         // 2 parities x 4 planes x 16384 u64 = 1 MB
#define WS_DUMP  (4096 + 1048576)            // 2*32*8*2048 u64 = 8 MB
#define WS_WI    (WS_DUMP + 8388608)         // hi 524288 f16, lo 524288 f16
#define WS_WO    (WS_WI + 2097152)           // 131072 f16

// staging plane offsets (u64 units) within one parity block of 65536
#define SP_HIA 0
#define SP_HIB 16384
#define SP_LOA 32768
#define SP_LOB 49152

union H8U { f16x8 h; u64 u[2]; };
union F4U { f32x4 f; u64 u[2]; };

__device__ __forceinline__ void cvt_hilo8(const float4 p0, const float4 p1, f16x8& hi, f16x8& lo) {
    float v[8] = {p0.x, p0.y, p0.z, p0.w, p1.x, p1.y, p1.z, p1.w};
#pragma unroll
    for (int j = 0; j < 8; ++j) {
        f16 h = (f16)v[j];
        hi[j] = h;
        lo[j] = (f16)(v[j] - (float)h);
    }
}

__device__ __forceinline__ int ld_flag(int* p) {
    return __hip_atomic_load(p, __ATOMIC_RELAXED, __HIP_MEMORY_SCOPE_AGENT);
}
__device__ __forceinline__ void st_flag(int* p, int v) {
    __hip_atomic_store(p, v, __ATOMIC_RELAXED, __HIP_MEMORY_SCOPE_AGENT);
}
// STORE side: 8B relaxed agent atomics (R1/R3-proven release class: ack at
// the LLC -> __syncthreads vmcnt-drain + flag store is a sound release).
__device__ __forceinline__ void st_u64a(u64* p, u64 v) {
    __hip_atomic_store(p, v, __ATOMIC_RELAXED, __HIP_MEMORY_SCOPE_AGENT);
}
// READ side: plain L1/L2-bypass load from the L3 coherence point. Issued
// only AFTER the producer's flag is observed; coalesces and pipelines.
__device__ __forceinline__ u64 ld8_sc(const u64* p) {
    u64 v;
    asm volatile("global_load_dwordx2 %0, %1, off sc0 sc1" : "=v"(v) : "v"(p));
    return v;
}
__device__ __forceinline__ void wait_vm0() {
    asm volatile("s_waitcnt vmcnt(0)" ::: "memory");
    __builtin_amdgcn_sched_barrier(0);   // rule #18: pin consumers after the wait
}
__device__ __forceinline__ void spin_ge(int* p, int target, long& budget) {
    while (budget > 0 && ld_flag(p) < target) {
        --budget;
        __builtin_amdgcn_s_sleep(2);
    }
}

// ------------------------------ prep kernels -------------------------------

__global__ void prep_wi(const float* __restrict__ Wi, f16* __restrict__ hi, f16* __restrict__ lo) {
    const int r    = blockIdx.x * 256 + threadIdx.x;    // [0, 65536)
    const int hblk = r >> 13, rem = r & 8191;
    const int kt = rem >> 10, rem2 = rem & 1023;
    const int nt = rem2 >> 6, lane = rem2 & 63;
    const int h = hblk * 256 + nt * 16 + (lane & 15);
    const int i = kt * 32 + (lane >> 4) * 8;
    const float* p = Wi + (long)h * 256 + i;
    float4 p0 = *(const float4*)p, p1 = *(const float4*)(p + 4);
    f16x8 vh, vl;
    cvt_hilo8(p0, p1, vh, vl);
    *(f16x8*)(hi + (long)r * 8) = vh;
    *(f16x8*)(lo + (long)r * 8) = vl;
}

__global__ void prep_wo(const float* __restrict__ Wo, f16* __restrict__ st) {
    const int r  = blockIdx.x * 256 + threadIdx.x;      // [0, 16384)
    const int nt = r >> 12, rem = r & 4095;
    const int kt = rem >> 6, lane = rem & 63;
    const int o = nt * 16 + (lane & 15);
    const int h = kt * 32 + (lane >> 4) * 8;
    const float* p = Wo + (long)o * 2048 + h;
    float4 p0 = *(const float4*)p, p1 = *(const float4*)(p + 4);
    float v[8] = {p0.x, p0.y, p0.z, p0.w, p1.x, p1.y, p1.z, p1.w};
    f16x8 a;
#pragma unroll
    for (int j = 0; j < 8; ++j) a[j] = (f16)v[j];
    *(f16x8*)(st + (long)r * 8) = a;
}

// writes the initial r-state staging in the plane layout (parity 0)
__global__ void prep_r0(const float* __restrict__ rate0, u64* __restrict__ rsU) {
    const int r   = blockIdx.x * 256 + threadIdx.x;     // frag index [0, 16384)
    const int ktg = r >> 8, rem = r & 255;
    const int mt = rem >> 6, lane = rem & 63;
    const int b = mt * 16 + (lane & 15);
    const int k = ktg * 32 + (lane >> 4) * 8;
    const float* p = rate0 + (long)b * 2048 + k;
    float4 p0 = *(const float4*)p, p1 = *(const float4*)(p + 4);
    H8U vh, vl;
    cvt_hilo8(p0, p1, vh.h, vl.h);
    rsU[SP_HIA + r] = vh.u[0];
    rsU[SP_HIB + r] = vh.u[1];
    rsU[SP_LOA + r] = vl.u[0];
    rsU[SP_LOB + r] = vl.u[1];
}

// ------------------------------- pre GEMM ----------------------------------
// pre[row][h] = X[row][:] . Wi[h][:] + bi[h]    row in [0, 32768), h in [0, 2048)

__global__ __launch_bounds__(256, 1) void pre_gemm(const float* __restrict__ X,
                                                   const f16* __restrict__ wih,
                                                   const f16* __restrict__ wil,
                                                   const float* __restrict__ bi,
                                                   float* __restrict__ pre) {
    const int wg = blockIdx.x;                 // 4096
    const int rowblk = wg >> 3, hblk = wg & 7; // hblk == XCD (L2 locality of Wi slice)
    const int tid = threadIdx.x, wv = tid >> 6, l = tid & 63;
    const int l15 = l & 15, lq = l >> 4;

    f16x8 Bh[8][4], Bl[8][4];  // 256 VGPR, persistent
#pragma unroll
    for (int kt = 0; kt < 8; ++kt)
#pragma unroll
        for (int nl = 0; nl < 4; ++nl) {
            const int  nt  = wv * 4 + nl;
            const long idx = (((long)(hblk * 8 + kt) * 16 + nt) * 64 + l) * 8;
            Bh[kt][nl] = *(const f16x8*)(wih + idx);
            Bl[kt][nl] = *(const f16x8*)(wil + idx);
        }
    float biv[4];
#pragma unroll
    for (int nl = 0; nl < 4; ++nl) biv[nl] = bi[hblk * 256 + (wv * 4 + nl) * 16 + l15];

#pragma unroll
    for (int mt = 0; mt < 4; ++mt) {
        const float* ap = X + (long)(rowblk * 64 + mt * 16 + l15) * 256 + lq * 8;
        f16x8 Ah[8], Al[8];
#pragma unroll
        for (int kt = 0; kt < 8; ++kt) {
            float4 p0 = *(const float4*)(ap + kt * 32);
            float4 p1 = *(const float4*)(ap + kt * 32 + 4);
            cvt_hilo8(p0, p1, Ah[kt], Al[kt]);
        }
        f32x4 acc[4] = {{0, 0, 0, 0}, {0, 0, 0, 0}, {0, 0, 0, 0}, {0, 0, 0, 0}};
#pragma unroll
        for (int kt = 0; kt < 8; ++kt)
#pragma unroll
            for (int nl = 0; nl < 4; ++nl) {
                acc[nl] = MFMA16(Al[kt], Bh[kt][nl], acc[nl]);
                acc[nl] = MFMA16(Ah[kt], Bl[kt][nl], acc[nl]);
                acc[nl] = MFMA16(Ah[kt], Bh[kt][nl], acc[nl]);
            }
#pragma unroll
        for (int nl = 0; nl < 4; ++nl)
#pragma unroll
            for (int q = 0; q < 4; ++q) {
                const int row = rowblk * 64 + mt * 16 + lq * 4 + q;
                const int h   = hblk * 256 + (wv * 4 + nl) * 16 + l15;
                pre[(long)row * 2048 + h] = acc[nl][q] + biv[nl];
            }
    }
}

// ------------------------------ scan kernel --------------------------------
// 256 WGs: hp = wg>>3 (h-slice of 64), s = wg&7 (k-shard of 256; == XCD).
// flagR[g] = t  <=> r_state(t) slice g published.  flagP[hp][s] = t+1 <=> partial(t) dumped.
// Stores: 8B relaxed agent atomics in u64 PLANES (R3).  Reads: plain sc0|sc1
// loads issued after the flag poll, drained with vmcnt(0)+sched_barrier.
// Release: payload atomics -> __syncthreads (vmcnt drain) -> flag store.

__global__ __launch_bounds__(256, 1) void scan_kernel(const float* __restrict__ Wh,
                                                      const float* __restrict__ bhp,
                                                      const float* __restrict__ rate0,
                                                      float* __restrict__ ra,   // pre in, rate_all out (in-place)
                                                      u64* __restrict__ rsU,    // staging planes, 2 parities
                                                      u64* __restrict__ dumpU,  // dump planes, 2 parities
                                                      int* flagP, int* flagR) {
    const int wg = blockIdx.x;
    const int hp = wg >> 3, s = wg & 7;
    const int tid = threadIdx.x, wv = tid >> 6, l = tid & 63;
    const int l15 = l & 15, lq = l >> 4;
    const bool is_red = (s == (hp & 7));
    __shared__ float lds[64 * 68];

    // Wh tile -> registers (hi/lo f16 frags). Lives across all steps.
    f16x8 WhH[8][4], WhL[8][4];
#pragma unroll
    for (int kt = 0; kt < 8; ++kt)
#pragma unroll
        for (int nt = 0; nt < 4; ++nt) {
            const float* p = Wh + (long)(hp * 64 + nt * 16 + l15) * 2048 + s * 256 + kt * 32 + lq * 8;
            float4 p0 = *(const float4*)p, p1 = *(const float4*)(p + 4);
            cvt_hilo8(p0, p1, WhH[kt][nt], WhL[kt][nt]);
        }

    float rf[4][4];  // f32 master state (reducers only), D-frag layout
    float bhv[4];
    if (is_red) {
#pragma unroll
        for (int nt = 0; nt < 4; ++nt) {
            bhv[nt] = bhp[hp * 64 + nt * 16 + l15];
#pragma unroll
            for (int q = 0; q < 4; ++q)
                rf[nt][q] = rate0[(long)(wv * 16 + lq * 4 + q) * 2048 + hp * 64 + nt * 16 + l15];
        }
    }

    long budget = SPIN_BUDGET;

    for (int t = 0; t < 512; ++t) {
        // prefetch pre[t] slice (reducers) - normal cached loads, written by a
        // prior kernel; overlaps the spins below.
        float pr[4][4];
        if (is_red) {
#pragma unroll
            for (int nt = 0; nt < 4; ++nt)
#pragma unroll
                for (int q = 0; q < 4; ++q)
                    pr[nt][q] = ra[((long)t * 64 + wv * 16 + lq * 4 + q) * 2048 + hp * 64 + nt * 16 + l15];
        }

        const u64* sb = rsU + (long)(t & 1) * 65536;   // staging parity block
        f32x4 acc[4] = {{0, 0, 0, 0}, {0, 0, 0, 0}, {0, 0, 0, 0}, {0, 0, 0, 0}};

#pragma unroll
        for (int i = 0; i < 4; ++i) {  // consume r slices incrementally as they arrive
            spin_ge(flagR + 4 * s + i, t, budget);
            __builtin_amdgcn_sched_barrier(0);
            H8U ah[2], al[2];
#pragma unroll
            for (int kk = 0; kk < 2; ++kk) {
                const int ktl = 2 * i + kk;
                const int f   = ((s * 8 + ktl) * 4 + wv) * 64 + l;   // frag index
                ah[kk].u[0] = ld8_sc(sb + SP_HIA + f);
                ah[kk].u[1] = ld8_sc(sb + SP_HIB + f);
                al[kk].u[0] = ld8_sc(sb + SP_LOA + f);
                al[kk].u[1] = ld8_sc(sb + SP_LOB + f);
            }
            wait_vm0();
#pragma unroll
            for (int kk = 0; kk < 2; ++kk) {  // same acc-update order as R3
                const int ktl = 2 * i + kk;
#pragma unroll
                for (int nt = 0; nt < 4; ++nt) {
                    acc[nt] = MFMA16(al[kk].h, WhH[ktl][nt], acc[nt]);
                    acc[nt] = MFMA16(ah[kk].h, WhL[ktl][nt], acc[nt]);
                    acc[nt] = MFMA16(ah[kk].h, WhH[ktl][nt], acc[nt]);
                }
            }
        }

        if (!is_red) {
            // dump accumulator in plane layout [j][tid] via atomic stores
            u64* dp = dumpU + ((long)(t & 1) * 256 + hp * 8 + s) * 2048;
#pragma unroll
            for (int nt = 0; nt < 4; ++nt) {
                F4U v; v.f = acc[nt];
                st_u64a(dp + (2 * nt + 0) * 256 + tid, v.u[0]);
                st_u64a(dp + (2 * nt + 1) * 256 + tid, v.u[1]);
            }
            __syncthreads();  // drains vmcnt -> atomics complete at LLC
            if (tid == 0) st_flag(flagP + hp * 8 + s, t + 1);
        } else {
            // lane-parallel wait for the 7 other shards (own shard in regs)
            {
                const int ss7  = tid & 7;
                const bool own = (ss7 == s);
                int* fp = flagP + hp * 8 + ss7;
                while (budget > 0 && !__all(own || (ld_flag(fp) >= t + 1))) {
                    --budget;
                    __builtin_amdgcn_s_sleep(2);
                }
                __builtin_amdgcn_sched_barrier(0);
            }

            // batch-issue ALL dump reads as plain sc loads (one wait).
            // own-shard slots load garbage (never stored) and are never used.
            // __launch_bounds__(256,1): 1 wave/SIMD -> VGPR headroom to 512,
            // so 64 u64 in flight do not spill.
            u64 gA[4][8], gB[4][8];   // [nt][ss]
            const u64* db = dumpU + ((long)(t & 1) * 256 + hp * 8) * 2048;
#pragma unroll
            for (int nt = 0; nt < 4; ++nt)
#pragma unroll
                for (int ss = 0; ss < 8; ++ss) {
                    gA[nt][ss] = ld8_sc(db + (long)ss * 2048 + (2 * nt + 0) * 256 + tid);
                    gB[nt][ss] = ld8_sc(db + (long)ss * 2048 + (2 * nt + 1) * 256 + tid);
                }
            wait_vm0();

            float u[4][4];
#pragma unroll
            for (int nt = 0; nt < 4; ++nt) {
                float s0 = 0.f, s1 = 0.f, s2 = 0.f, s3 = 0.f;
#pragma unroll
                for (int ss = 0; ss < 8; ++ss) {  // ss ascending: FP order identical to R3
                    F4U x;
                    if (ss == s) { x.f = acc[nt]; }
                    else         { x.u[0] = gA[nt][ss]; x.u[1] = gB[nt][ss]; }
                    s0 += x.f[0]; s1 += x.f[1]; s2 += x.f[2]; s3 += x.f[3];
                }
                u[nt][0] = s0; u[nt][1] = s1; u[nt][2] = s2; u[nt][3] = s3;
            }

#pragma unroll
            for (int nt = 0; nt < 4; ++nt)
#pragma unroll
                for (int q = 0; q < 4; ++q) {
                    const float uu = u[nt][q] + pr[nt][q] + bhv[nt];
                    const float rn = tanhf(uu);
                    rf[nt][q] = 0.9f * rf[nt][q] + 0.1f * rn;
                }

            // transpose D-frag -> A-frag layout via LDS, republish hi/lo f16
            // planes (publish FIRST; rate_all HBM write off the critical path)
#pragma unroll
            for (int nt = 0; nt < 4; ++nt)
#pragma unroll
                for (int q = 0; q < 4; ++q)
                    lds[(wv * 16 + lq * 4 + q) * 68 + nt * 16 + l15] = rf[nt][q];
            __syncthreads();
            u64* sbn = rsU + (long)((t + 1) & 1) * 65536;
#pragma unroll
            for (int i2 = 0; i2 < 2; ++i2) {
                const int c = tid + i2 * 256;
                const int b = c & 63, h8 = c >> 6;
                const float* lp = lds + b * 68 + h8 * 8;
                float4 p0 = *(const float4*)lp, p1 = *(const float4*)(lp + 4);
                H8U hi8, lo8;
                cvt_hilo8(p0, p1, hi8.h, lo8.h);
                const int k0 = hp * 64 + h8 * 8;
                const int f  = ((k0 >> 5) * 4 + (b >> 4)) * 64 + ((b & 15) | (((k0 >> 3) & 3) << 4));
                st_u64a(sbn + SP_HIA + f, hi8.u[0]);
                st_u64a(sbn + SP_HIB + f, hi8.u[1]);
                st_u64a(sbn + SP_LOA + f, lo8.u[0]);
                st_u64a(sbn + SP_LOB + f, lo8.u[1]);
            }
            __syncthreads();  // all staging atomics drained across the WG
            if (tid == 0) st_flag(flagR + hp, t + 1);

            // rate_all write (normal cached stores; only read by out_gemm
            // after kernel end) - off the critical path
#pragma unroll
            for (int nt = 0; nt < 4; ++nt)
#pragma unroll
                for (int q = 0; q < 4; ++q)
                    ra[((long)t * 64 + wv * 16 + lq * 4 + q) * 2048 + hp * 64 + nt * 16 + l15] = rf[nt][q];
        }
    }
}

// ------------------------------- out GEMM ----------------------------------
// out[row][o] = rate_all[row][:] . Wo[o][:] + bo[o]

__global__ __launch_bounds__(256, 1) void out_gemm(const float* __restrict__ ra,
                                                   const f16* __restrict__ wo,
                                                   const float* __restrict__ bo,
                                                   float* __restrict__ out) {
    const int wg = blockIdx.x, tid = threadIdx.x, wv = tid >> 6, l = tid & 63;
    const int l15 = l & 15, lq = l >> 4;
    const long rowbase = (long)wg * 64;
    f32x4 acc[4] = {{0, 0, 0, 0}, {0, 0, 0, 0}, {0, 0, 0, 0}, {0, 0, 0, 0}};
    const float bov = bo[wv * 16 + l15];
#pragma unroll 4
    for (int kt = 0; kt < 64; ++kt) {
        f16x8 B = *(const f16x8*)(wo + ((long)(wv * 64 + kt) * 64 + l) * 8);
#pragma unroll
        for (int mt = 0; mt < 4; ++mt) {
            const float* ap = ra + (rowbase + mt * 16 + l15) * 2048 + kt * 32 + lq * 8;
            float4 p0 = *(const float4*)ap, p1 = *(const float4*)(ap + 4);
            float v[8] = {p0.x, p0.y, p0.z, p0.w, p1.x, p1.y, p1.z, p1.w};
            f16x8 a;
#pragma unroll
            for (int j = 0; j < 8; ++j) a[j] = (f16)v[j];
            acc[mt] = MFMA16(a, B, acc[mt]);
        }
    }
#pragma unroll
    for (int mt = 0; mt < 4; ++mt)
#pragma unroll
        for (int q = 0; q < 4; ++q)
            out[(rowbase + mt * 16 + lq * 4 + q) * 64 + wv * 16 + l15] = acc[mt][q] + bov;
}

// ------------------------------ launch -------------------------------------

extern "C" void kernel_launch(void* const* d_in, const int* in_sizes, int n_in,
                              void* d_out, int out_size, void* d_ws, size_t ws_size,
                              hipStream_t stream) {
    const float* input = (const float*)d_in[0];
    const float* rate0 = (const float*)d_in[1];
    const float* Wi    = (const float*)d_in[2];
    const float* bi    = (const float*)d_in[3];
    const float* Wh    = (const float*)d_in[4];
    const float* bh    = (const float*)d_in[5];
    const float* Wo    = (const float*)d_in[6];
    const float* bo    = (const float*)d_in[7];

    float* out      = (float*)d_out;
    float* rate_all = out + OUT0_ELEMS;  // pre written here, then overwritten in place

    char* w      = (char*)d_ws;
    int*  flagP  = (int*)(w + WS_FLAGP);
    int*  flagR  = (int*)(w + WS_FLAGR);
    u64*  rsU    = (u64*)(w + WS_RSTG);
    u64*  dumpU  = (u64*)(w + WS_DUMP);
    f16*  wi_hi  = (f16*)(w + WS_WI);
    f16*  wi_lo  = wi_hi + 524288;
    f16*  wo_st  = (f16*)(w + WS_WO);

    hipMemsetAsync(d_ws, 0, 4096, stream);  // zero flags every launch
    prep_wi<<<256, 256, 0, stream>>>(Wi, wi_hi, wi_lo);
    prep_wo<<<64, 256, 0, stream>>>(Wo, wo_st);
    prep_r0<<<64, 256, 0, stream>>>(rate0, rsU);
    pre_gemm<<<4096, 256, 0, stream>>>(input, wi_hi, wi_lo, bi, rate_all);
    scan_kernel<<<256, 256, 0, stream>>>(Wh, bh, rate0, rate_all,
                                         rsU, dumpU, flagP, flagR);
    out_gemm<<<512, 256, 0, stream>>>(rate_all, wo_st, bo, out);
}

// Round 6
// 4254.887 us; speedup vs baseline: 6.2076x; 1.5514x over previous
//
#include <hip/hip_runtime.h>
#include <hip/hip_fp16.h>

// ---------------------------------------------------------------------------
// RNN chaotic scan, MI355X.
//   T=512, B=64, I=256, H=2048, O=64, alpha=0.1
// R6: R5 falsified the intra-XCD plain-sc0 release (absmax 2.25) -> memory
// classes frozen at R4's proven set: 8B relaxed agent-atomic STORES (release,
// ack at LLC) + plain sc0|sc1 LOADS after flag poll (acquire) + atomic flags.
// This round removes the REDUCER BOTTLENECK instead: all 256 WGs become
// sub-reducers. WG (hp,s) reduces batch slice b in [8s,8s+8) of its row:
// dump partial -> wait row's 8 flagP -> read 1 u64/shard/thread (8x parallel
// across the machine) -> 2 tanh/thread -> publish 2KB staging slice with
// per-sub flag flagRs[hp*8+s]. Sum order ss-ascending over ALL 8 shards (own
// value read back from memory = bit-exact) -> trajectory bit-identical to R4.
// Staging consume upgraded to 16B dwordx4 MALL loads (16 vs 32 transactions).
// WAR safety: same transitive all-to-all chain as R4 (publish(t) <- row
// flagP(t) <- consume(t) <- all-rows flagRs(t) <- every WG's t-1 reads).
// ---------------------------------------------------------------------------

typedef _Float16 f16;
typedef _Float16 f16x8 __attribute__((ext_vector_type(8)));
typedef float    f32x4 __attribute__((ext_vector_type(4)));
typedef unsigned long long u64;

#define MFMA16(a, b, c) __builtin_amdgcn_mfma_f32_16x16x32_f16((a), (b), (c), 0, 0, 0)

#define OUT0_ELEMS  2097152   // T*B*O floats; rate_all follows in d_out
#define SPIN_BUDGET (1L << 22)

// ws layout (bytes)
#define WS_FLAGP 0            // 256 ints: flagP[hp*8+s]
#define WS_FLAGR 1024         // 256 ints: flagRs[hp*8+s]
#define WS_RSTG  4096         // rh0, rl0, rh1, rl1 : 4 x 131072 f16 = 1 MB
#define WS_DUMP  (4096 + 1048576)            // 2*32*8*2048 u64 = 8 MB
#define WS_WI    (WS_DUMP + 8388608)         // hi 524288 f16, lo 524288 f16
#define WS_WO    (WS_WI + 2097152)           // 131072 f16

union H8U { f16x8 h; u64 u[2]; };
union F4U { f32x4 f; u64 u[2]; };
union U2F { u64 u; float f[2]; };

__device__ __forceinline__ void cvt_hilo8(const float4 p0, const float4 p1, f16x8& hi, f16x8& lo) {
    float v[8] = {p0.x, p0.y, p0.z, p0.w, p1.x, p1.y, p1.z, p1.w};
#pragma unroll
    for (int j = 0; j < 8; ++j) {
        f16 h = (f16)v[j];
        hi[j] = h;
        lo[j] = (f16)(v[j] - (float)h);
    }
}

// ---- proven memory classes (R4) -------------------------------------------
__device__ __forceinline__ int ld_flag(int* p) {
    return __hip_atomic_load(p, __ATOMIC_RELAXED, __HIP_MEMORY_SCOPE_AGENT);
}
__device__ __forceinline__ void st_flag(int* p, int v) {
    __hip_atomic_store(p, v, __ATOMIC_RELAXED, __HIP_MEMORY_SCOPE_AGENT);
}
__device__ __forceinline__ void st_u64a(u64* p, u64 v) {   // release-class store
    __hip_atomic_store(p, v, __ATOMIC_RELAXED, __HIP_MEMORY_SCOPE_AGENT);
}
__device__ __forceinline__ u64 ld8_sc(const u64* p) {      // acquire-class load (8B)
    u64 v;
    asm volatile("global_load_dwordx2 %0, %1, off sc0 sc1" : "=v"(v) : "v"(p));
    return v;
}
__device__ __forceinline__ f16x8 ld16h_sc(const f16* p) {  // acquire-class load (16B)
    f16x8 v;
    asm volatile("global_load_dwordx4 %0, %1, off sc0 sc1" : "=v"(v) : "v"(p));
    return v;
}
__device__ __forceinline__ void wait_vm0() {
    asm volatile("s_waitcnt vmcnt(0)" ::: "memory");
    __builtin_amdgcn_sched_barrier(0);   // rule #18: pin consumers after the wait
}

// ------------------------------ prep kernels -------------------------------

__global__ void prep_wi(const float* __restrict__ Wi, f16* __restrict__ hi, f16* __restrict__ lo) {
    const int r    = blockIdx.x * 256 + threadIdx.x;    // [0, 65536)
    const int hblk = r >> 13, rem = r & 8191;
    const int kt = rem >> 10, rem2 = rem & 1023;
    const int nt = rem2 >> 6, lane = rem2 & 63;
    const int h = hblk * 256 + nt * 16 + (lane & 15);
    const int i = kt * 32 + (lane >> 4) * 8;
    const float* p = Wi + (long)h * 256 + i;
    float4 p0 = *(const float4*)p, p1 = *(const float4*)(p + 4);
    f16x8 vh, vl;
    cvt_hilo8(p0, p1, vh, vl);
    *(f16x8*)(hi + (long)r * 8) = vh;
    *(f16x8*)(lo + (long)r * 8) = vl;
}

__global__ void prep_wo(const float* __restrict__ Wo, f16* __restrict__ st) {
    const int r  = blockIdx.x * 256 + threadIdx.x;      // [0, 16384)
    const int nt = r >> 12, rem = r & 4095;
    const int kt = rem >> 6, lane = rem & 63;
    const int o = nt * 16 + (lane & 15);
    const int h = kt * 32 + (lane >> 4) * 8;
    const float* p = Wo + (long)o * 2048 + h;
    float4 p0 = *(const float4*)p, p1 = *(const float4*)(p + 4);
    float v[8] = {p0.x, p0.y, p0.z, p0.w, p1.x, p1.y, p1.z, p1.w};
    f16x8 a;
#pragma unroll
    for (int j = 0; j < 8; ++j) a[j] = (f16)v[j];
    *(f16x8*)(st + (long)r * 8) = a;
}

// initial r-state staging: 16B-contiguous frag layout (parity 0)
__global__ void prep_r0(const float* __restrict__ rate0, f16* __restrict__ hi, f16* __restrict__ lo) {
    const int r   = blockIdx.x * 256 + threadIdx.x;     // frag index [0, 16384)
    const int ktg = r >> 8, rem = r & 255;
    const int mt = rem >> 6, lane = rem & 63;
    const int b = mt * 16 + (lane & 15);
    const int k = ktg * 32 + (lane >> 4) * 8;
    const float* p = rate0 + (long)b * 2048 + k;
    float4 p0 = *(const float4*)p, p1 = *(const float4*)(p + 4);
    f16x8 vh, vl;
    cvt_hilo8(p0, p1, vh, vl);
    *(f16x8*)(hi + (long)r * 8) = vh;
    *(f16x8*)(lo + (long)r * 8) = vl;
}

// ------------------------------- pre GEMM ----------------------------------
// pre[row][h] = X[row][:] . Wi[h][:] + bi[h]    row in [0, 32768), h in [0, 2048)

__global__ __launch_bounds__(256, 1) void pre_gemm(const float* __restrict__ X,
                                                   const f16* __restrict__ wih,
                                                   const f16* __restrict__ wil,
                                                   const float* __restrict__ bi,
                                                   float* __restrict__ pre) {
    const int wg = blockIdx.x;                 // 4096
    const int rowblk = wg >> 3, hblk = wg & 7; // hblk == XCD (L2 locality of Wi slice)
    const int tid = threadIdx.x, wv = tid >> 6, l = tid & 63;
    const int l15 = l & 15, lq = l >> 4;

    f16x8 Bh[8][4], Bl[8][4];  // 256 VGPR, persistent
#pragma unroll
    for (int kt = 0; kt < 8; ++kt)
#pragma unroll
        for (int nl = 0; nl < 4; ++nl) {
            const int  nt  = wv * 4 + nl;
            const long idx = (((long)(hblk * 8 + kt) * 16 + nt) * 64 + l) * 8;
            Bh[kt][nl] = *(const f16x8*)(wih + idx);
            Bl[kt][nl] = *(const f16x8*)(wil + idx);
        }
    float biv[4];
#pragma unroll
    for (int nl = 0; nl < 4; ++nl) biv[nl] = bi[hblk * 256 + (wv * 4 + nl) * 16 + l15];

#pragma unroll
    for (int mt = 0; mt < 4; ++mt) {
        const float* ap = X + (long)(rowblk * 64 + mt * 16 + l15) * 256 + lq * 8;
        f16x8 Ah[8], Al[8];
#pragma unroll
        for (int kt = 0; kt < 8; ++kt) {
            float4 p0 = *(const float4*)(ap + kt * 32);
            float4 p1 = *(const float4*)(ap + kt * 32 + 4);
            cvt_hilo8(p0, p1, Ah[kt], Al[kt]);
        }
        f32x4 acc[4] = {{0, 0, 0, 0}, {0, 0, 0, 0}, {0, 0, 0, 0}, {0, 0, 0, 0}};
#pragma unroll
        for (int kt = 0; kt < 8; ++kt)
#pragma unroll
            for (int nl = 0; nl < 4; ++nl) {
                acc[nl] = MFMA16(Al[kt], Bh[kt][nl], acc[nl]);
                acc[nl] = MFMA16(Ah[kt], Bl[kt][nl], acc[nl]);
                acc[nl] = MFMA16(Ah[kt], Bh[kt][nl], acc[nl]);
            }
#pragma unroll
        for (int nl = 0; nl < 4; ++nl)
#pragma unroll
            for (int q = 0; q < 4; ++q) {
                const int row = rowblk * 64 + mt * 16 + lq * 4 + q;
                const int h   = hblk * 256 + (wv * 4 + nl) * 16 + l15;
                pre[(long)row * 2048 + h] = acc[nl][q] + biv[nl];
            }
    }
}

// ------------------------------ scan kernel --------------------------------
// 256 WGs: hp = wg>>3 (h-slice of 64), s = wg&7 (k-shard of 256).
// ALL WGs are symmetric sub-reducers: WG (hp,s) owns batch slice [8s,8s+8) of
// row hp. flagP[hp*8+s]=t+1 <=> partial(t) dumped. flagRs[hp*8+s]=t+1 <=>
// staging slice (b in [8s,8s+8), row hp) of r(t) published.
// Stores: atomic u64 (release). Reads: plain sc0|sc1 after flag (acquire).

__global__ __launch_bounds__(256, 1) void scan_kernel(const float* __restrict__ Wh,
                                                      const float* __restrict__ bhp,
                                                      const float* __restrict__ rate0,
                                                      float* __restrict__ ra,   // pre in, rate_all out (in-place)
                                                      f16* __restrict__ rh0, f16* __restrict__ rl0,
                                                      f16* __restrict__ rh1, f16* __restrict__ rl1,
                                                      u64* __restrict__ dumpU,
                                                      int* flagP, int* flagRs) {
    const int wg = blockIdx.x;
    const int hp = wg >> 3, s = wg & 7;
    const int tid = threadIdx.x, wv = tid >> 6, l = tid & 63;
    const int l15 = l & 15, lq = l >> 4;
    __shared__ float lds[8 * 68];

    // Wh tile -> registers (hi/lo f16 frags). Lives across all steps.
    f16x8 WhH[8][4], WhL[8][4];
#pragma unroll
    for (int kt = 0; kt < 8; ++kt)
#pragma unroll
        for (int nt = 0; nt < 4; ++nt) {
            const float* p = Wh + (long)(hp * 64 + nt * 16 + l15) * 2048 + s * 256 + kt * 32 + lq * 8;
            float4 p0 = *(const float4*)p, p1 = *(const float4*)(p + 4);
            cvt_hilo8(p0, p1, WhH[kt][nt], WhL[kt][nt]);
        }

    // sub-reduce slot mapping: thread handles 2 elements (b_r, b_r+1) x h_r
    const int nt_r = tid >> 6, j_r = (tid >> 5) & 1, c_r = tid & 31;
    const int src_tid = (s >> 1) * 64 + ((s & 1) * 2 + (c_r >> 4)) * 16 + (c_r & 15);
    const int slot    = (2 * nt_r + j_r) * 256 + src_tid;
    const int b_r     = s * 8 + (c_r >> 4) * 4 + 2 * j_r;   // and b_r+1
    const int h_r     = hp * 64 + nt_r * 16 + (c_r & 15);
    const int b_loc   = (c_r >> 4) * 4 + 2 * j_r;           // 0..7 within slice
    const int h_loc   = nt_r * 16 + (c_r & 15);             // 0..63 within row

    const float bh2 = bhp[h_r];
    float rf0 = rate0[(long)b_r * 2048 + h_r];              // f32 master state
    float rf1 = rate0[(long)(b_r + 1) * 2048 + h_r];

    long budget = SPIN_BUDGET;

    for (int t = 0; t < 512; ++t) {
        // prefetch pre[t] for this thread's 2 elements (cached loads)
        const float pr0 = ra[((long)t * 64 + b_r) * 2048 + h_r];
        const float pr1 = ra[((long)t * 64 + b_r + 1) * 2048 + h_r];

        const f16* rh = (t & 1) ? rh1 : rh0;
        const f16* rl = (t & 1) ? rl1 : rl0;
        f32x4 acc[4] = {{0, 0, 0, 0}, {0, 0, 0, 0}, {0, 0, 0, 0}, {0, 0, 0, 0}};

#pragma unroll
        for (int i = 0; i < 4; ++i) {  // consume r slices incrementally as they arrive
            {   // poll the 8 sub-flags of row 4s+i (lane-parallel)
                int* fr = flagRs + (4 * s + i) * 8 + (tid & 7);
                while (budget > 0 && !__all(ld_flag(fr) >= t)) {
                    --budget;
                    __builtin_amdgcn_s_sleep(2);
                }
                __builtin_amdgcn_sched_barrier(0);
            }
            f16x8 ah[2], al[2];
#pragma unroll
            for (int kk = 0; kk < 2; ++kk) {
                const int  ktl = 2 * i + kk;
                const long off = ((long)((s * 8 + ktl) * 4 + wv) * 64 + l) * 8;  // f16 elems
                ah[kk] = ld16h_sc(rh + off);
                al[kk] = ld16h_sc(rl + off);
            }
            wait_vm0();
#pragma unroll
            for (int kk = 0; kk < 2; ++kk) {  // same acc-update order as R4
                const int ktl = 2 * i + kk;
#pragma unroll
                for (int nt = 0; nt < 4; ++nt) {
                    acc[nt] = MFMA16(al[kk], WhH[ktl][nt], acc[nt]);
                    acc[nt] = MFMA16(ah[kk], WhL[ktl][nt], acc[nt]);
                    acc[nt] = MFMA16(ah[kk], WhH[ktl][nt], acc[nt]);
                }
            }
        }

        // dump own partial (ALL WGs; atomic release-class stores)
        {
            u64* dp = dumpU + ((long)(t & 1) * 256 + hp * 8 + s) * 2048;
#pragma unroll
            for (int nt = 0; nt < 4; ++nt) {
                F4U v; v.f = acc[nt];
                st_u64a(dp + (2 * nt + 0) * 256 + tid, v.u[0]);
                st_u64a(dp + (2 * nt + 1) * 256 + tid, v.u[1]);
            }
        }
        __syncthreads();  // drains vmcnt -> atomics complete at LLC
        if (tid == 0) st_flag(flagP + hp * 8 + s, t + 1);

        {   // wait for all 8 shards of own row (lane-parallel; own is trivially set)
            int* fp = flagP + hp * 8 + (tid & 7);
            while (budget > 0 && !__all(ld_flag(fp) >= t + 1)) {
                --budget;
                __builtin_amdgcn_s_sleep(2);
            }
            __builtin_amdgcn_sched_barrier(0);
        }

        // read this thread's slot from all 8 shard dumps (batched, one wait)
        u64 g[8];
        {
            const u64* db = dumpU + ((long)(t & 1) * 256 + hp * 8) * 2048;
#pragma unroll
            for (int ss = 0; ss < 8; ++ss) g[ss] = ld8_sc(db + (long)ss * 2048 + slot);
            wait_vm0();
        }
        float u0 = 0.f, u1 = 0.f;
#pragma unroll
        for (int ss = 0; ss < 8; ++ss) {  // ss ascending: FP order identical to R4
            U2F w; w.u = g[ss];
            u0 += w.f[0];
            u1 += w.f[1];
        }

        {
            const float rn0 = tanhf(u0 + pr0 + bh2);
            const float rn1 = tanhf(u1 + pr1 + bh2);
            rf0 = 0.9f * rf0 + 0.1f * rn0;
            rf1 = 0.9f * rf1 + 0.1f * rn1;
        }

        // transpose slice (8b x 64h) via LDS, republish hi/lo f16 frags
        lds[b_loc * 68 + h_loc]       = rf0;
        lds[(b_loc + 1) * 68 + h_loc] = rf1;
        __syncthreads();
        {
            f16* wh_ = (t & 1) ? rh0 : rh1;  // buffer (t+1)&1
            f16* wl_ = (t & 1) ? rl0 : rl1;
            if (tid < 64) {
                const int bl = tid >> 3, h8 = tid & 7;
                const int b  = s * 8 + bl;
                const float* lp = lds + bl * 68 + h8 * 8;
                float4 p0 = *(const float4*)lp, p1 = *(const float4*)(lp + 4);
                H8U hi8, lo8;
                cvt_hilo8(p0, p1, hi8.h, lo8.h);
                const int  k0   = hp * 64 + h8 * 8;
                const long idx2 = ((long)((k0 >> 5) * 4 + (b >> 4)) * 64 + ((b & 15) | (((k0 >> 3) & 3) << 4)));
                st_u64a((u64*)wh_ + idx2 * 2,     hi8.u[0]);
                st_u64a((u64*)wh_ + idx2 * 2 + 1, hi8.u[1]);
                st_u64a((u64*)wl_ + idx2 * 2,     lo8.u[0]);
                st_u64a((u64*)wl_ + idx2 * 2 + 1, lo8.u[1]);
            }
        }
        __syncthreads();  // all staging atomics drained across the WG
        if (tid == 0) st_flag(flagRs + hp * 8 + s, t + 1);

        // rate_all write (normal cached stores; read by out_gemm after kernel
        // end) - off the critical path
        ra[((long)t * 64 + b_r) * 2048 + h_r]     = rf0;
        ra[((long)t * 64 + b_r + 1) * 2048 + h_r] = rf1;
    }
}

// ------------------------------- out GEMM ----------------------------------
// out[row][o] = rate_all[row][:] . Wo[o][:] + bo[o]

__global__ __launch_bounds__(256, 1) void out_gemm(const float* __restrict__ ra,
                                                   const f16* __restrict__ wo,
                                                   const float* __restrict__ bo,
                                                   float* __restrict__ out) {
    const int wg = blockIdx.x, tid = threadIdx.x, wv = tid >> 6, l = tid & 63;
    const int l15 = l & 15, lq = l >> 4;
    const long rowbase = (long)wg * 64;
    f32x4 acc[4] = {{0, 0, 0, 0}, {0, 0, 0, 0}, {0, 0, 0, 0}, {0, 0, 0, 0}};
    const float bov = bo[wv * 16 + l15];
#pragma unroll 4
    for (int kt = 0; kt < 64; ++kt) {
        f16x8 B = *(const f16x8*)(wo + ((long)(wv * 64 + kt) * 64 + l) * 8);
#pragma unroll
        for (int mt = 0; mt < 4; ++mt) {
            const float* ap = ra + (rowbase + mt * 16 + l15) * 2048 + kt * 32 + lq * 8;
            float4 p0 = *(const float4*)ap, p1 = *(const float4*)(ap + 4);
            float v[8] = {p0.x, p0.y, p0.z, p0.w, p1.x, p1.y, p1.z, p1.w};
            f16x8 a;
#pragma unroll
            for (int j = 0; j < 8; ++j) a[j] = (f16)v[j];
            acc[mt] = MFMA16(a, B, acc[mt]);
        }
    }
#pragma unroll
    for (int mt = 0; mt < 4; ++mt)
#pragma unroll
        for (int q = 0; q < 4; ++q)
            out[(rowbase + mt * 16 + lq * 4 + q) * 64 + wv * 16 + l15] = acc[mt][q] + bov;
}

// ------------------------------ launch -------------------------------------

extern "C" void kernel_launch(void* const* d_in, const int* in_sizes, int n_in,
                              void* d_out, int out_size, void* d_ws, size_t ws_size,
                              hipStream_t stream) {
    const float* input = (const float*)d_in[0];
    const float* rate0 = (const float*)d_in[1];
    const float* Wi    = (const float*)d_in[2];
    const float* bi    = (const float*)d_in[3];
    const float* Wh    = (const float*)d_in[4];
    const float* bh    = (const float*)d_in[5];
    const float* Wo    = (const float*)d_in[6];
    const float* bo    = (const float*)d_in[7];

    float* out      = (float*)d_out;
    float* rate_all = out + OUT0_ELEMS;  // pre written here, then overwritten in place

    char* w      = (char*)d_ws;
    int*  flagP  = (int*)(w + WS_FLAGP);
    int*  flagRs = (int*)(w + WS_FLAGR);
    f16*  rs     = (f16*)(w + WS_RSTG);
    f16*  rh0    = rs;
    f16*  rl0    = rs + 131072;
    f16*  rh1    = rs + 262144;
    f16*  rl1    = rs + 393216;
    u64*  dumpU  = (u64*)(w + WS_DUMP);
    f16*  wi_hi  = (f16*)(w + WS_WI);
    f16*  wi_lo  = wi_hi + 524288;
    f16*  wo_st  = (f16*)(w + WS_WO);

    hipMemsetAsync(d_ws, 0, 4096, stream);  // zero flags every launch
    prep_wi<<<256, 256, 0, stream>>>(Wi, wi_hi, wi_lo);
    prep_wo<<<64, 256, 0, stream>>>(Wo, wo_st);
    prep_r0<<<64, 256, 0, stream>>>(rate0, rh0, rl0);
    pre_gemm<<<4096, 256, 0, stream>>>(input, wi_hi, wi_lo, bi, rate_all);
    scan_kernel<<<256, 256, 0, stream>>>(Wh, bh, rate0, rate_all,
                                         rh0, rl0, rh1, rl1, dumpU, flagP, flagRs);
    out_gemm<<<512, 256, 0, stream>>>(rate_all, wo_st, bo, out);
}